// Round 21
// baseline (383.178 us; speedup 1.0000x reference)
//
#include <hip/hip_runtime.h>
#include <hip/hip_bf16.h>

#define B_ 4
#define S_ 2048
#define D_ 1024
#define H_ 16
#define M_ 8192   // B_*S_

typedef __attribute__((ext_vector_type(8))) _Float16 h8;
typedef __attribute__((ext_vector_type(4))) _Float16 h4;
typedef __attribute__((ext_vector_type(2))) __fp16   fp16x2;
typedef __attribute__((ext_vector_type(8))) short    s8;
typedef __attribute__((ext_vector_type(4))) float    f4;

#define AS1(p) ((const __attribute__((address_space(1))) void*)(p))
#define AS3(p) ((__attribute__((address_space(3))) void*)(p))

__device__ __forceinline__ f4 mfma16(h8 a, h8 b, f4 c) {
  return __builtin_amdgcn_mfma_f32_16x16x32_f16(a, b, c, 0, 0, 0);
}

// ---------------- cast f32 -> f16 (weights only: Wq,Wk,Wv,Wo) ----------------
struct CastArgs {
  const float* src[4];
  _Float16*    dst[4];
  int cum[5];
};

__global__ __launch_bounds__(256) void cast_kernel(CastArgs a) {
  int idx = blockIdx.x * 256 + threadIdx.x;
  if (idx >= a.cum[4]) return;
  int seg = 0;
#pragma unroll
  for (int s = 1; s < 4; ++s) seg += (idx >= a.cum[s]) ? 1 : 0;
  size_t off = (size_t)(idx - a.cum[seg]) * 8;
  const float4* sp = (const float4*)(a.src[seg] + off);
  float4 u = sp[0], v = sp[1];
  union { _Float16 h[8]; h8 v8; } o;
  o.h[0] = (_Float16)u.x; o.h[1] = (_Float16)u.y;
  o.h[2] = (_Float16)u.z; o.h[3] = (_Float16)u.w;
  o.h[4] = (_Float16)v.x; o.h[5] = (_Float16)v.y;
  o.h[6] = (_Float16)v.z; o.h[7] = (_Float16)v.w;
  *(h8*)(a.dst[seg] + off) = o.v8;
}

// ---------------- merged Q/K/V projection GEMM, pipelined f32->f16 A-path -----
// (round-20 validated) loads for tile kt+64 issue BEFORE COMPUTE(kt); converted
// ds_writes land after the post-compute barrier. 2 barriers/tile.
struct QKVArgs {
  const float*    A[3];
  const _Float16* Bt[3];
  const float*    bias[3];
  _Float16*       out[3];
};

__global__ __launch_bounds__(256, 3) void gemm_qkv(QKVArgs ga, float scaleQ) {
  __shared__ __align__(16) _Float16 Alds[128 * 64];   // 16 KB f16
  __shared__ __align__(16) _Float16 Blds[128 * 64];   // 16 KB
  const int z = blockIdx.z;
  const float*    A  = ga.A[z];
  const _Float16* Bt = ga.Bt[z];
  const float*  bias = ga.bias[z];
  _Float16*     Cout = ga.out[z];
  const float scale  = (z == 0) ? scaleQ : 1.0f;
  const int t = threadIdx.x;
  const int lane = t & 63, w = t >> 6;
  const int wm = w >> 1, wn = w & 1;
  const int m0 = blockIdx.x * 128, n0 = blockIdx.y * 128;
  const int ll = lane & 15, lg = lane >> 4;
  f4 acc[4][4] = {};

  int arow[4], acc_[4];
#pragma unroll
  for (int qq = 0; qq < 4; ++qq) {
    int c2 = qq * 256 + t;
    arow[qq] = c2 >> 3;
    acc_[qq] = c2 & 7;
  }

  float4 a0[4], a1[4];
  auto LOADR = [&](int kt) {
#pragma unroll
    for (int qq = 0; qq < 4; ++qq) {
      const float* src = A + (size_t)(m0 + arow[qq]) * 1024 + kt + acc_[qq] * 8;
      a0[qq] = *(const float4*)src;
      a1[qq] = *(const float4*)(src + 4);
    }
  };
  auto WRITEA = [&]() {
#pragma unroll
    for (int qq = 0; qq < 4; ++qq) {
      union { _Float16 hh[8]; h8 v; } cv;
      cv.hh[0] = (_Float16)a0[qq].x; cv.hh[1] = (_Float16)a0[qq].y;
      cv.hh[2] = (_Float16)a0[qq].z; cv.hh[3] = (_Float16)a0[qq].w;
      cv.hh[4] = (_Float16)a1[qq].x; cv.hh[5] = (_Float16)a1[qq].y;
      cv.hh[6] = (_Float16)a1[qq].z; cv.hh[7] = (_Float16)a1[qq].w;
      *(h8*)((char*)Alds + arow[qq] * 128 + ((acc_[qq] ^ (arow[qq] & 7)) << 4)) = cv.v;
    }
  };
  auto GLOADB = [&](int kt) {
#pragma unroll
    for (int i = 0; i < 4; ++i) {
      int slot = i * 256 + t;
      int r = slot >> 3;
      int gs = ((slot & 7) ^ (r & 7)) * 8;
      __builtin_amdgcn_global_load_lds(AS1(Bt + (size_t)(n0 + r) * 1024 + kt + gs),
                                       AS3((char*)Blds + (i * 256 + w * 64) * 16), 16, 0, 0);
    }
  };

  LOADR(0);
  WRITEA();
  GLOADB(0);
  __syncthreads();

  for (int kt = 0; kt < 1024; kt += 64) {
    if (kt < 960) LOADR(kt + 64);
#pragma unroll
    for (int ks = 0; ks < 2; ++ks) {
      h8 af[4], bf[4];
#pragma unroll
      for (int im = 0; im < 4; ++im) {
        int R = wm * 64 + im * 16 + ll;
        af[im] = *(const h8*)((const char*)Alds + R * 128 + (((ks * 4 + lg) ^ (R & 7)) << 4));
      }
#pragma unroll
      for (int in = 0; in < 4; ++in) {
        int R = wn * 64 + in * 16 + ll;
        bf[in] = *(const h8*)((const char*)Blds + R * 128 + (((ks * 4 + lg) ^ (R & 7)) << 4));
      }
#pragma unroll
      for (int im = 0; im < 4; ++im)
#pragma unroll
        for (int in = 0; in < 4; ++in)
          acc[im][in] = mfma16(af[im], bf[in], acc[im][in]);
    }
    __syncthreads();
    if (kt < 960) {
      WRITEA();
      GLOADB(kt + 64);
    }
    __syncthreads();
  }
#pragma unroll
  for (int im = 0; im < 4; ++im)
#pragma unroll
    for (int in = 0; in < 4; ++in) {
      int col = n0 + wn * 64 + in * 16 + ll;
      float bv = bias[col];
      if (z == 2) {
        int row0 = m0 + wm * 64 + im * 16 + lg * 4;
        int bb = row0 >> 11, s = row0 & 2047;
        union { _Float16 hh[4]; unsigned long long u; } pk;
#pragma unroll
        for (int r = 0; r < 4; ++r)
          pk.hh[r] = (_Float16)(acc[im][in][r] + bv);
        *(unsigned long long*)(Cout + (size_t)((bb * 16 + (col >> 6)) * 64 + (col & 63)) * S_ + s) = pk.u;
      } else {
#pragma unroll
        for (int r = 0; r < 4; ++r) {
          int row = m0 + wm * 64 + im * 16 + lg * 4 + r;
          Cout[(size_t)row * 1024 + col] = (_Float16)((acc[im][in][r] + bv) * scale);
        }
      }
    }
}

// ---------------- output projection GEMM (f16 A, f32 out) — unchanged --------
__global__ __launch_bounds__(256, 3) void gemm_out(
    const _Float16* __restrict__ A,
    const _Float16* __restrict__ Bt,
    const float*    __restrict__ bias,
    float*          __restrict__ Cout)
{
  __shared__ __align__(16) _Float16 Alds[128 * 64];
  __shared__ __align__(16) _Float16 Blds[128 * 64];
  const int t = threadIdx.x;
  const int lane = t & 63, w = t >> 6;
  const int wm = w >> 1, wn = w & 1;
  const int m0 = blockIdx.x * 128, n0 = blockIdx.y * 128;
  const int ll = lane & 15, lg = lane >> 4;
  f4 acc[4][4] = {};

  for (int kt = 0; kt < 1024; kt += 64) {
    __syncthreads();
#pragma unroll
    for (int i = 0; i < 4; ++i) {
      int slot = i * 256 + t;
      int r = slot >> 3;
      int gs = ((slot & 7) ^ (r & 7)) * 8;
      __builtin_amdgcn_global_load_lds(AS1(A  + (size_t)(m0 + r) * 1024 + kt + gs),
                                       AS3((char*)Alds + (i * 256 + w * 64) * 16), 16, 0, 0);
      __builtin_amdgcn_global_load_lds(AS1(Bt + (size_t)(n0 + r) * 1024 + kt + gs),
                                       AS3((char*)Blds + (i * 256 + w * 64) * 16), 16, 0, 0);
    }
    __syncthreads();
#pragma unroll
    for (int ks = 0; ks < 2; ++ks) {
      h8 af[4], bf[4];
#pragma unroll
      for (int im = 0; im < 4; ++im) {
        int R = wm * 64 + im * 16 + ll;
        af[im] = *(const h8*)((const char*)Alds + R * 128 + (((ks * 4 + lg) ^ (R & 7)) << 4));
      }
#pragma unroll
      for (int in = 0; in < 4; ++in) {
        int R = wn * 64 + in * 16 + ll;
        bf[in] = *(const h8*)((const char*)Blds + R * 128 + (((ks * 4 + lg) ^ (R & 7)) << 4));
      }
#pragma unroll
      for (int im = 0; im < 4; ++im)
#pragma unroll
        for (int in = 0; in < 4; ++in)
          acc[im][in] = mfma16(af[im], bf[in], acc[im][in]);
    }
  }
#pragma unroll
  for (int im = 0; im < 4; ++im)
#pragma unroll
    for (int in = 0; in < 4; ++in) {
      int col = n0 + wn * 64 + in * 16 + ll;
      float bv = bias[col];
#pragma unroll
      for (int r = 0; r < 4; ++r) {
        int row = m0 + wm * 64 + im * 16 + lg * 4 + r;
        Cout[(size_t)row * 1024 + col] = acc[im][in][r] + bv;
      }
    }
}

// ---------------- fused flash attention + inline bias -------------------------
// Round-16/18/20 validated sync structure (one barrier/body). Data-path change
// only: bias computed inline from td/mask. Raw gathers (4x f4 + 4x int4) issue
// mid-body exactly where the biasN BLOAD was; conversion (exp2) happens AFTER
// the end-of-body barrier (loads had softmax+PV+barrier to land; register deps
// compiler-waitcnt'd). Eliminates the bias_kernel dispatch + 134MB of traffic.
#define KL_OFF   0
#define VL_OFF   16384
#define PL_OFF   32768

__global__ __launch_bounds__(512, 2) void attn_kernel(
    const _Float16* __restrict__ Qp,    // [8192][1024], pre-scaled by 1/(8 ln2)
    const _Float16* __restrict__ Kp,    // [8192][1024]
    const _Float16* __restrict__ Vt,    // [(b*16+h)*64+hd][2048]
    const float*    __restrict__ td,    // [4][2048][2048]
    const int*      __restrict__ mask,  // [4][2048][2048]
    const float*    __restrict__ gptr,
    _Float16*       __restrict__ Oa)    // [8192][1024]
{
  __shared__ __align__(16) char lds[49152];
  const int t = threadIdx.x;
  const int lane = t & 63, w = t >> 6;          // w = 0..7
  const int ll = lane & 15, lg = lane >> 4;
  // XCD-chunked swizzle (grid 1024 = 8 XCD x 128)
  const int vbid = ((int)blockIdx.x & 7) * 128 + ((int)blockIdx.x >> 3);
  const int b  = vbid >> 8;
  const int h  = (vbid >> 4) & 15;
  const int qg = vbid & 15;
  const int q0 = qg * 128 + w * 16;     // wave q base

  const int lrow = lane >> 3;           // staging row-in-group
  const int lcs  = (lane & 7) ^ lrow;   // pre-swizzled chunk

  const float gamma = gptr[0];
  const float g2 = gamma * 1.4426950408889634f;   // exp(-g t) = 2^(-g2 t)

  const _Float16* Kg = Kp + (size_t)b * S_ * D_ + h * 64;
  const _Float16* Vg = Vt + (size_t)(b * 16 + h) * 64 * S_;
  const size_t  brow = ((size_t)b * S_ + q0 + ll) * S_;   // per-lane row q
  const float*  Tg = td + brow;
  const int*    Mg = mask + brow;

  char* pbase = lds + PL_OFF + w * 2048;

  // Q fragments (B-operand of swapped QK)
  const size_t qrow = (size_t)(b * S_ + q0 + ll) * D_ + h * 64;
  h8 qf0 = *(const h8*)(Qp + qrow + lg * 8);
  h8 qf1 = *(const h8*)(Qp + qrow + 32 + lg * 8);

  float lsum = 0.f;                     // all elements of this lane are q = ll
  f4 accO[4] = {};                      // O^T[d = df*16+lg*4+r][q = ll]

  // stage one 64-k K/V tile: 16 gloads distributed 2-per-wave over 8 waves
  auto STAGE = [&](int kt, int bufb) {
#pragma unroll
    for (int j = 0; j < 2; ++j) {
      int i = w * 2 + j;                // 0..15
      int g = i & 7;
      int row8 = g * 8 + lrow;
      const _Float16* src;
      char* dst;
      if (i < 8) {
        src = Kg + (size_t)(kt + row8) * D_ + lcs * 8;
        dst = lds + KL_OFF + bufb * 8192 + g * 1024;
      } else {
        src = Vg + (size_t)row8 * S_ + kt + lcs * 8;
        dst = lds + VL_OFF + bufb * 8192 + g * 1024;
      }
      __builtin_amdgcn_global_load_lds(AS1(src), AS3(dst), 16, 0, 0);
    }
  };

  f4   tdN[4];                          // raw td gather (next tile)
  int4 mkN[4];                          // raw mask gather (next tile)
  f4   bias_cur[4];                     // converted bias for current tile

  auto RAWLOAD = [&](int kt) {
#pragma unroll
    for (int jf = 0; jf < 4; ++jf) {
      tdN[jf] = *(const f4*)(Tg + kt + 16 * jf + lg * 4);
      mkN[jf] = *(const int4*)(Mg + kt + 16 * jf + lg * 4);
    }
  };
  auto CONV1 = [&](float tv, int mv) -> float {
    float p, x = -g2 * tv;
    asm("v_exp_f32 %0, %1" : "=v"(p) : "v"(x));
    return mv ? p * 1.4426950408889634f : -30000.0f;
  };
  auto CONV = [&]() {
#pragma unroll
    for (int jf = 0; jf < 4; ++jf) {
      bias_cur[jf][0] = CONV1(tdN[jf][0], mkN[jf].x);
      bias_cur[jf][1] = CONV1(tdN[jf][1], mkN[jf].y);
      bias_cur[jf][2] = CONV1(tdN[jf][2], mkN[jf].z);
      bias_cur[jf][3] = CONV1(tdN[jf][3], mkN[jf].w);
    }
  };

  auto BODY = [&](int tt) {
    const int bufb = tt & 1;
    const char* Kb = lds + KL_OFF + bufb * 8192;
    const char* Vb = lds + VL_OFF + bufb * 8192;

    // S^T = K . Q^T, bias as MFMA C-init.
    f4 accS[4];
#pragma unroll
    for (int jf = 0; jf < 4; ++jf) accS[jf] = bias_cur[jf];
    __builtin_amdgcn_s_setprio(1);
#pragma unroll
    for (int jf = 0; jf < 4; ++jf) {
      int row = jf * 16 + ll;
      h8 k0 = *(const h8*)(Kb + row * 128 + (((lg)     ^ (row & 7)) << 4));
      h8 k1 = *(const h8*)(Kb + row * 128 + (((4 + lg) ^ (row & 7)) << 4));
      accS[jf] = mfma16(k0, qf0, accS[jf]);
      accS[jf] = mfma16(k1, qf1, accS[jf]);
    }
    __builtin_amdgcn_s_setprio(0);

    // issue next tile mid-body (K/V -> LDS, td/mask -> regs)
    if (tt < 31) {
      STAGE((tt + 1) * 64, bufb ^ 1);
      RAWLOAD((tt + 1) * 64);
    }

    // P^T = 2^(S^T); pack pairs along k (regs) -> one ds_write_b64 per jf
#pragma unroll
    for (int jf = 0; jf < 4; ++jf) {
      float p0, p1, p2, p3;
      asm("v_exp_f32 %0, %1" : "=v"(p0) : "v"(accS[jf][0]));
      asm("v_exp_f32 %0, %1" : "=v"(p1) : "v"(accS[jf][1]));
      asm("v_exp_f32 %0, %1" : "=v"(p2) : "v"(accS[jf][2]));
      asm("v_exp_f32 %0, %1" : "=v"(p3) : "v"(accS[jf][3]));
      lsum += (p0 + p1) + (p2 + p3);
      union { fp16x2 h[2]; unsigned long long u; } wv;
      wv.h[0] = __builtin_amdgcn_cvt_pkrtz(p0, p1);
      wv.h[1] = __builtin_amdgcn_cvt_pkrtz(p2, p3);
      *(unsigned long long*)(pbase + ll * 128 + ((32 * jf + 8 * lg) ^ ((ll & 7) << 4))) = wv.u;
    }

    // O^T += V^T . P^T
    __builtin_amdgcn_s_setprio(1);
#pragma unroll
    for (int ks = 0; ks < 2; ++ks) {
      h8 pf = *(const h8*)(pbase + ll * 128 + ((ks * 64 + lg * 16) ^ ((ll & 7) << 4)));
#pragma unroll
      for (int df = 0; df < 4; ++df) {
        int vrow = df * 16 + ll;
        h8 vfr = *(const h8*)(Vb + vrow * 128 + (((ks * 4 + lg) ^ (vrow & 7)) << 4));
        accO[df] = mfma16(vfr, pf, accO[df]);
      }
    }
    __builtin_amdgcn_s_setprio(0);

    __syncthreads();   // drains stage(tt+1) + WAR for buf[bufb]
    if (tt < 31) CONV();   // convert next tile's bias (loads landed long ago)
  };

  // prologue
  STAGE(0, 0);
  RAWLOAD(0);
  __syncthreads();     // tile 0 resident for all waves
  CONV();

  for (int tt = 0; tt < 32; ++tt) BODY(tt);

  // final: sum partials across the 4 lg-groups holding the same q = ll
  lsum += __shfl_xor(lsum, 16);
  lsum += __shfl_xor(lsum, 32);
  float linv = 1.0f / lsum;
#pragma unroll
  for (int df = 0; df < 4; ++df)
#pragma unroll
    for (int r = 0; r < 4; ++r) {
      size_t orow = (size_t)(b * S_ + q0 + ll) * D_ + h * 64 + df * 16 + lg * 4 + r;
      Oa[orow] = (_Float16)(accO[df][r] * linv);
    }
}

// ---------------- launcher ----------------
extern "C" void kernel_launch(void* const* d_in, const int* in_sizes, int n_in,
                              void* d_out, int out_size, void* d_ws, size_t ws_size,
                              hipStream_t stream) {
  const float* q    = (const float*)d_in[0];
  const float* k    = (const float*)d_in[1];
  const float* v    = (const float*)d_in[2];
  const float* td   = (const float*)d_in[3];
  const int*   mask = (const int*)d_in[4];
  const float* Wq   = (const float*)d_in[5];
  const float* bq   = (const float*)d_in[6];
  const float* Wk   = (const float*)d_in[7];
  const float* bk   = (const float*)d_in[8];
  const float* Wv   = (const float*)d_in[9];
  const float* bv   = (const float*)d_in[10];
  const float* Wo   = (const float*)d_in[11];
  const float* bo   = (const float*)d_in[12];
  const float* gm   = (const float*)d_in[13];

  const size_t MD = (size_t)M_ * D_;      // 8388608
  const size_t WW = (size_t)D_ * D_;      // 1048576
  if (ws_size < (8 * MD + 4 * WW) * sizeof(_Float16)) return;

  _Float16* base = (_Float16*)d_ws;
  _Float16* qh = base;                    // unused
  _Float16* kh = qh + MD;                 // unused
  _Float16* vh = kh + MD;                 // unused
  _Float16* wq = vh + MD;
  _Float16* wk = wq + WW;
  _Float16* wv = wk + WW;
  _Float16* wo = wv + WW;
  _Float16* Qp = wo + WW;
  _Float16* Kp = Qp + MD;
  _Float16* Vp = Kp + MD;                 // unused
  _Float16* Vt = Vp + MD;
  _Float16* Oa = Vt + MD;

  // cast only the 4 weight matrices to f16
  CastArgs ca;
  ca.src[0] = Wq; ca.src[1] = Wk; ca.src[2] = Wv; ca.src[3] = Wo;
  ca.dst[0] = wq; ca.dst[1] = wk; ca.dst[2] = wv; ca.dst[3] = wo;
  int c = 0; ca.cum[0] = 0;
  for (int i = 0; i < 4; ++i) { c += (int)(WW / 8); ca.cum[i + 1] = c; }
  cast_kernel<<<(c + 255) / 256, 256, 0, stream>>>(ca);

  // merged Q/K/V projections, A pipelined-reg-staged from f32 inputs
  QKVArgs ga;
  ga.A[0] = q;  ga.A[1] = k;  ga.A[2] = v;
  ga.Bt[0] = wq; ga.Bt[1] = wk; ga.Bt[2] = wv;
  ga.bias[0] = bq; ga.bias[1] = bk; ga.bias[2] = bv;
  ga.out[0] = Qp; ga.out[1] = Kp; ga.out[2] = Vt;
  gemm_qkv<<<dim3(64, 8, 3), 256, 0, stream>>>(ga, 0.18033688011112042f);

  attn_kernel<<<1024, 512, 0, stream>>>(Qp, Kp, Vt, td, mask, gm, Oa);
  gemm_out<<<dim3(64, 8), 256, 0, stream>>>(Oa, wo, bo, (float*)d_out);
}

// Round 22
// 291.679 us; speedup vs baseline: 1.3137x; 1.3137x over previous
//
#include <hip/hip_runtime.h>
#include <hip/hip_bf16.h>

#define B_ 4
#define S_ 2048
#define D_ 1024
#define H_ 16
#define M_ 8192   // B_*S_

typedef __attribute__((ext_vector_type(8))) _Float16 h8;
typedef __attribute__((ext_vector_type(4))) _Float16 h4;
typedef __attribute__((ext_vector_type(2))) __fp16   fp16x2;
typedef __attribute__((ext_vector_type(8))) short    s8;
typedef __attribute__((ext_vector_type(4))) float    f4;

#define AS1(p) ((const __attribute__((address_space(1))) void*)(p))
#define AS3(p) ((__attribute__((address_space(3))) void*)(p))

__device__ __forceinline__ f4 mfma16(h8 a, h8 b, f4 c) {
  return __builtin_amdgcn_mfma_f32_16x16x32_f16(a, b, c, 0, 0, 0);
}

// ---------------- cast f32 -> f16 (weights only: Wq,Wk,Wv,Wo) ----------------
struct CastArgs {
  const float* src[4];
  _Float16*    dst[4];
  int cum[5];
};

__global__ __launch_bounds__(256) void cast_kernel(CastArgs a) {
  int idx = blockIdx.x * 256 + threadIdx.x;
  if (idx >= a.cum[4]) return;
  int seg = 0;
#pragma unroll
  for (int s = 1; s < 4; ++s) seg += (idx >= a.cum[s]) ? 1 : 0;
  size_t off = (size_t)(idx - a.cum[seg]) * 8;
  const float4* sp = (const float4*)(a.src[seg] + off);
  float4 u = sp[0], v = sp[1];
  union { _Float16 h[8]; h8 v8; } o;
  o.h[0] = (_Float16)u.x; o.h[1] = (_Float16)u.y;
  o.h[2] = (_Float16)u.z; o.h[3] = (_Float16)u.w;
  o.h[4] = (_Float16)v.x; o.h[5] = (_Float16)v.y;
  o.h[6] = (_Float16)v.z; o.h[7] = (_Float16)v.w;
  *(h8*)(a.dst[seg] + off) = o.v8;
}

// ---------------- merged Q/K/V projection GEMM + bias precompute --------------
// z=0..2: pipelined f32->f16 A-path GEMM (round-20 validated).
// z=3:    bias precompute (round-13 validated math), grid-stride over the
//         B*S*S/8 chunks: biasN = mask ? exp(-g*td)/ln2 : -30000 (f16).
//         Memory-bound; overlaps with the GEMM slices' compute-bound tail.
struct QKVArgs {
  const float*    A[3];
  const _Float16* Bt[3];
  const float*    bias[3];
  _Float16*       out[3];
  const float*    td;
  const int*      mask;
  const float*    gptr;
  _Float16*       biasN;
};

__global__ __launch_bounds__(256, 3) void gemm_qkv(QKVArgs ga, float scaleQ) {
  __shared__ __align__(16) _Float16 Alds[128 * 64];   // 16 KB f16
  __shared__ __align__(16) _Float16 Blds[128 * 64];   // 16 KB
  const int z = blockIdx.z;
  const int t = threadIdx.x;

  if (z == 3) {
    // ---- bias precompute slice: 512 blocks x 256 thr x 16 chunks ----
    const float gamma = ga.gptr[0];
    size_t tid = ((size_t)blockIdx.x * 8 + blockIdx.y) * 256 + t;
#pragma unroll
    for (int i = 0; i < 16; ++i) {
      size_t off = (tid + (size_t)i * 131072) * 8;   // 512*256 = 131072 threads
      const float4* tp = (const float4*)(ga.td + off);
      const int4*   mp = (const int4*)(ga.mask + off);
      float4 t0 = tp[0], t1 = tp[1];
      int4   m0 = mp[0], m1 = mp[1];
      union { _Float16 h[8]; h8 v8; } o;
      o.h[0] = m0.x ? (_Float16)(__expf(-gamma * t0.x) * 1.4426950408889634f) : (_Float16)(-30000.0f);
      o.h[1] = m0.y ? (_Float16)(__expf(-gamma * t0.y) * 1.4426950408889634f) : (_Float16)(-30000.0f);
      o.h[2] = m0.z ? (_Float16)(__expf(-gamma * t0.z) * 1.4426950408889634f) : (_Float16)(-30000.0f);
      o.h[3] = m0.w ? (_Float16)(__expf(-gamma * t0.w) * 1.4426950408889634f) : (_Float16)(-30000.0f);
      o.h[4] = m1.x ? (_Float16)(__expf(-gamma * t1.x) * 1.4426950408889634f) : (_Float16)(-30000.0f);
      o.h[5] = m1.y ? (_Float16)(__expf(-gamma * t1.y) * 1.4426950408889634f) : (_Float16)(-30000.0f);
      o.h[6] = m1.z ? (_Float16)(__expf(-gamma * t1.z) * 1.4426950408889634f) : (_Float16)(-30000.0f);
      o.h[7] = m1.w ? (_Float16)(__expf(-gamma * t1.w) * 1.4426950408889634f) : (_Float16)(-30000.0f);
      *(h8*)(ga.biasN + off) = o.v8;
    }
    return;
  }

  const float*    A  = ga.A[z];
  const _Float16* Bt = ga.Bt[z];
  const float*  bias = ga.bias[z];
  _Float16*     Cout = ga.out[z];
  const float scale  = (z == 0) ? scaleQ : 1.0f;
  const int lane = t & 63, w = t >> 6;
  const int wm = w >> 1, wn = w & 1;
  const int m0 = blockIdx.x * 128, n0 = blockIdx.y * 128;
  const int ll = lane & 15, lg = lane >> 4;
  f4 acc[4][4] = {};

  int arow[4], acc_[4];
#pragma unroll
  for (int qq = 0; qq < 4; ++qq) {
    int c2 = qq * 256 + t;
    arow[qq] = c2 >> 3;
    acc_[qq] = c2 & 7;
  }

  float4 a0[4], a1[4];
  auto LOADR = [&](int kt) {
#pragma unroll
    for (int qq = 0; qq < 4; ++qq) {
      const float* src = A + (size_t)(m0 + arow[qq]) * 1024 + kt + acc_[qq] * 8;
      a0[qq] = *(const float4*)src;
      a1[qq] = *(const float4*)(src + 4);
    }
  };
  auto WRITEA = [&]() {
#pragma unroll
    for (int qq = 0; qq < 4; ++qq) {
      union { _Float16 hh[8]; h8 v; } cv;
      cv.hh[0] = (_Float16)a0[qq].x; cv.hh[1] = (_Float16)a0[qq].y;
      cv.hh[2] = (_Float16)a0[qq].z; cv.hh[3] = (_Float16)a0[qq].w;
      cv.hh[4] = (_Float16)a1[qq].x; cv.hh[5] = (_Float16)a1[qq].y;
      cv.hh[6] = (_Float16)a1[qq].z; cv.hh[7] = (_Float16)a1[qq].w;
      *(h8*)((char*)Alds + arow[qq] * 128 + ((acc_[qq] ^ (arow[qq] & 7)) << 4)) = cv.v;
    }
  };
  auto GLOADB = [&](int kt) {
#pragma unroll
    for (int i = 0; i < 4; ++i) {
      int slot = i * 256 + t;
      int r = slot >> 3;
      int gs = ((slot & 7) ^ (r & 7)) * 8;
      __builtin_amdgcn_global_load_lds(AS1(Bt + (size_t)(n0 + r) * 1024 + kt + gs),
                                       AS3((char*)Blds + (i * 256 + w * 64) * 16), 16, 0, 0);
    }
  };

  LOADR(0);
  WRITEA();
  GLOADB(0);
  __syncthreads();

  for (int kt = 0; kt < 1024; kt += 64) {
    if (kt < 960) LOADR(kt + 64);
#pragma unroll
    for (int ks = 0; ks < 2; ++ks) {
      h8 af[4], bf[4];
#pragma unroll
      for (int im = 0; im < 4; ++im) {
        int R = wm * 64 + im * 16 + ll;
        af[im] = *(const h8*)((const char*)Alds + R * 128 + (((ks * 4 + lg) ^ (R & 7)) << 4));
      }
#pragma unroll
      for (int in = 0; in < 4; ++in) {
        int R = wn * 64 + in * 16 + ll;
        bf[in] = *(const h8*)((const char*)Blds + R * 128 + (((ks * 4 + lg) ^ (R & 7)) << 4));
      }
#pragma unroll
      for (int im = 0; im < 4; ++im)
#pragma unroll
        for (int in = 0; in < 4; ++in)
          acc[im][in] = mfma16(af[im], bf[in], acc[im][in]);
    }
    __syncthreads();
    if (kt < 960) {
      WRITEA();
      GLOADB(kt + 64);
    }
    __syncthreads();
  }
#pragma unroll
  for (int im = 0; im < 4; ++im)
#pragma unroll
    for (int in = 0; in < 4; ++in) {
      int col = n0 + wn * 64 + in * 16 + ll;
      float bv = bias[col];
      if (z == 2) {
        int row0 = m0 + wm * 64 + im * 16 + lg * 4;
        int bb = row0 >> 11, s = row0 & 2047;
        union { _Float16 hh[4]; unsigned long long u; } pk;
#pragma unroll
        for (int r = 0; r < 4; ++r)
          pk.hh[r] = (_Float16)(acc[im][in][r] + bv);
        *(unsigned long long*)(Cout + (size_t)((bb * 16 + (col >> 6)) * 64 + (col & 63)) * S_ + s) = pk.u;
      } else {
#pragma unroll
        for (int r = 0; r < 4; ++r) {
          int row = m0 + wm * 64 + im * 16 + lg * 4 + r;
          Cout[(size_t)row * 1024 + col] = (_Float16)((acc[im][in][r] + bv) * scale);
        }
      }
    }
}

// ---------------- output projection GEMM (f16 A, f32 out) — unchanged --------
__global__ __launch_bounds__(256, 3) void gemm_out(
    const _Float16* __restrict__ A,
    const _Float16* __restrict__ Bt,
    const float*    __restrict__ bias,
    float*          __restrict__ Cout)
{
  __shared__ __align__(16) _Float16 Alds[128 * 64];
  __shared__ __align__(16) _Float16 Blds[128 * 64];
  const int t = threadIdx.x;
  const int lane = t & 63, w = t >> 6;
  const int wm = w >> 1, wn = w & 1;
  const int m0 = blockIdx.x * 128, n0 = blockIdx.y * 128;
  const int ll = lane & 15, lg = lane >> 4;
  f4 acc[4][4] = {};

  for (int kt = 0; kt < 1024; kt += 64) {
    __syncthreads();
#pragma unroll
    for (int i = 0; i < 4; ++i) {
      int slot = i * 256 + t;
      int r = slot >> 3;
      int gs = ((slot & 7) ^ (r & 7)) * 8;
      __builtin_amdgcn_global_load_lds(AS1(A  + (size_t)(m0 + r) * 1024 + kt + gs),
                                       AS3((char*)Alds + (i * 256 + w * 64) * 16), 16, 0, 0);
      __builtin_amdgcn_global_load_lds(AS1(Bt + (size_t)(n0 + r) * 1024 + kt + gs),
                                       AS3((char*)Blds + (i * 256 + w * 64) * 16), 16, 0, 0);
    }
    __syncthreads();
#pragma unroll
    for (int ks = 0; ks < 2; ++ks) {
      h8 af[4], bf[4];
#pragma unroll
      for (int im = 0; im < 4; ++im) {
        int R = wm * 64 + im * 16 + ll;
        af[im] = *(const h8*)((const char*)Alds + R * 128 + (((ks * 4 + lg) ^ (R & 7)) << 4));
      }
#pragma unroll
      for (int in = 0; in < 4; ++in) {
        int R = wn * 64 + in * 16 + ll;
        bf[in] = *(const h8*)((const char*)Blds + R * 128 + (((ks * 4 + lg) ^ (R & 7)) << 4));
      }
#pragma unroll
      for (int im = 0; im < 4; ++im)
#pragma unroll
        for (int in = 0; in < 4; ++in)
          acc[im][in] = mfma16(af[im], bf[in], acc[im][in]);
    }
  }
#pragma unroll
  for (int im = 0; im < 4; ++im)
#pragma unroll
    for (int in = 0; in < 4; ++in) {
      int col = n0 + wn * 64 + in * 16 + ll;
      float bv = bias[col];
#pragma unroll
      for (int r = 0; r < 4; ++r) {
        int row = m0 + wm * 64 + im * 16 + lg * 4 + r;
        Cout[(size_t)row * 1024 + col] = acc[im][in][r] + bv;
      }
    }
}

// ---------------- fused flash attention (round-16/18/20 validated) ------------
// 8 waves/block = 128 q-rows; per-wave 16 q-rows; K/V LDS double-buffered,
// swapped QK with biasN C-init, packed P, one barrier/body, setprio clusters.
// LDS 48KB -> 3 blocks/CU = 24 waves/CU; launch_bounds(512,2) keeps VGPR ~60.
#define KL_OFF   0
#define VL_OFF   16384
#define PL_OFF   32768

__global__ __launch_bounds__(512, 2) void attn_kernel(
    const _Float16* __restrict__ Qp,    // [8192][1024], pre-scaled by 1/(8 ln2)
    const _Float16* __restrict__ Kp,    // [8192][1024]
    const _Float16* __restrict__ Vt,    // [(b*16+h)*64+hd][2048]
    const _Float16* __restrict__ biasN, // [4][2048(q)][2048(k)], pre-scaled 1/ln2
    _Float16*       __restrict__ Oa)    // [8192][1024]
{
  __shared__ __align__(16) char lds[49152];
  const int t = threadIdx.x;
  const int lane = t & 63, w = t >> 6;          // w = 0..7
  const int ll = lane & 15, lg = lane >> 4;
  // XCD-chunked swizzle (grid 1024 = 8 XCD x 128)
  const int vbid = ((int)blockIdx.x & 7) * 128 + ((int)blockIdx.x >> 3);
  const int b  = vbid >> 8;
  const int h  = (vbid >> 4) & 15;
  const int qg = vbid & 15;
  const int q0 = qg * 128 + w * 16;     // wave q base

  const int lrow = lane >> 3;           // staging row-in-group
  const int lcs  = (lane & 7) ^ lrow;   // pre-swizzled chunk

  const _Float16* Kg = Kp + (size_t)b * S_ * D_ + h * 64;
  const _Float16* Vg = Vt + (size_t)(b * 16 + h) * 64 * S_;
  const _Float16* Bg = biasN + ((size_t)b * S_ + q0 + ll) * S_;  // per-lane row q

  char* pbase = lds + PL_OFF + w * 2048;

  // Q fragments (B-operand of swapped QK)
  const size_t qrow = (size_t)(b * S_ + q0 + ll) * D_ + h * 64;
  h8 qf0 = *(const h8*)(Qp + qrow + lg * 8);
  h8 qf1 = *(const h8*)(Qp + qrow + 32 + lg * 8);

  float lsum = 0.f;                     // all elements of this lane are q = ll
  f4 accO[4] = {};                      // O^T[d = df*16+lg*4+r][q = ll]

  // stage one 64-k K/V tile: 16 gloads distributed 2-per-wave over 8 waves
  auto STAGE = [&](int kt, int bufb) {
#pragma unroll
    for (int j = 0; j < 2; ++j) {
      int i = w * 2 + j;                // 0..15
      int g = i & 7;
      int row8 = g * 8 + lrow;
      const _Float16* src;
      char* dst;
      if (i < 8) {
        src = Kg + (size_t)(kt + row8) * D_ + lcs * 8;
        dst = lds + KL_OFF + bufb * 8192 + g * 1024;
      } else {
        src = Vg + (size_t)row8 * S_ + kt + lcs * 8;
        dst = lds + VL_OFF + bufb * 8192 + g * 1024;
      }
      __builtin_amdgcn_global_load_lds(AS1(src), AS3(dst), 16, 0, 0);
    }
  };
  auto BLOAD = [&](int kt, h4 (&dst)[4]) {
#pragma unroll
    for (int jf = 0; jf < 4; ++jf)
      dst[jf] = *(const h4*)(Bg + kt + 16 * jf + lg * 4);
  };

  auto BODY = [&](int tt, h4 (&bc)[4], h4 (&bn)[4]) {
    const int bufb = tt & 1;
    const char* Kb = lds + KL_OFF + bufb * 8192;
    const char* Vb = lds + VL_OFF + bufb * 8192;

    // S^T = K . Q^T, bias as MFMA C-init.
    f4 accS[4];
#pragma unroll
    for (int jf = 0; jf < 4; ++jf) {
      accS[jf][0] = (float)bc[jf][0];
      accS[jf][1] = (float)bc[jf][1];
      accS[jf][2] = (float)bc[jf][2];
      accS[jf][3] = (float)bc[jf][3];
    }
    __builtin_amdgcn_s_setprio(1);
#pragma unroll
    for (int jf = 0; jf < 4; ++jf) {
      int row = jf * 16 + ll;
      h8 k0 = *(const h8*)(Kb + row * 128 + (((lg)     ^ (row & 7)) << 4));
      h8 k1 = *(const h8*)(Kb + row * 128 + (((4 + lg) ^ (row & 7)) << 4));
      accS[jf] = mfma16(k0, qf0, accS[jf]);
      accS[jf] = mfma16(k1, qf1, accS[jf]);
    }
    __builtin_amdgcn_s_setprio(0);

    // issue next tile mid-body: drained by the end-of-body __syncthreads
    if (tt < 31) {
      STAGE((tt + 1) * 64, bufb ^ 1);
      BLOAD((tt + 1) * 64, bn);
    }

    // P^T = 2^(S^T); pack pairs along k (regs) -> one ds_write_b64 per jf
#pragma unroll
    for (int jf = 0; jf < 4; ++jf) {
      float p0, p1, p2, p3;
      asm("v_exp_f32 %0, %1" : "=v"(p0) : "v"(accS[jf][0]));
      asm("v_exp_f32 %0, %1" : "=v"(p1) : "v"(accS[jf][1]));
      asm("v_exp_f32 %0, %1" : "=v"(p2) : "v"(accS[jf][2]));
      asm("v_exp_f32 %0, %1" : "=v"(p3) : "v"(accS[jf][3]));
      lsum += (p0 + p1) + (p2 + p3);
      union { fp16x2 h[2]; unsigned long long u; } wv;
      wv.h[0] = __builtin_amdgcn_cvt_pkrtz(p0, p1);
      wv.h[1] = __builtin_amdgcn_cvt_pkrtz(p2, p3);
      *(unsigned long long*)(pbase + ll * 128 + ((32 * jf + 8 * lg) ^ ((ll & 7) << 4))) = wv.u;
    }

    // O^T += V^T . P^T
    __builtin_amdgcn_s_setprio(1);
#pragma unroll
    for (int ks = 0; ks < 2; ++ks) {
      h8 pf = *(const h8*)(pbase + ll * 128 + ((ks * 64 + lg * 16) ^ ((ll & 7) << 4)));
#pragma unroll
      for (int df = 0; df < 4; ++df) {
        int vrow = df * 16 + ll;
        h8 vfr = *(const h8*)(Vb + vrow * 128 + (((ks * 4 + lg) ^ (vrow & 7)) << 4));
        accO[df] = mfma16(vfr, pf, accO[df]);
      }
    }
    __builtin_amdgcn_s_setprio(0);

    __syncthreads();   // drains stage(tt+1) + WAR for buf[bufb]
  };

  h4 bA[4], bB[4];

  // prologue
  STAGE(0, 0);
  BLOAD(0, bA);
  __syncthreads();     // tile 0 resident for all waves

  for (int tt = 0; tt < 32; tt += 2) {  // 2x unroll: bias regs ping-pong
    BODY(tt,     bA, bB);
    BODY(tt + 1, bB, bA);
  }

  // final: sum partials across the 4 lg-groups holding the same q = ll
  lsum += __shfl_xor(lsum, 16);
  lsum += __shfl_xor(lsum, 32);
  float linv = 1.0f / lsum;
#pragma unroll
  for (int df = 0; df < 4; ++df)
#pragma unroll
    for (int r = 0; r < 4; ++r) {
      size_t orow = (size_t)(b * S_ + q0 + ll) * D_ + h * 64 + df * 16 + lg * 4 + r;
      Oa[orow] = (_Float16)(accO[df][r] * linv);
    }
}

// ---------------- launcher ----------------
extern "C" void kernel_launch(void* const* d_in, const int* in_sizes, int n_in,
                              void* d_out, int out_size, void* d_ws, size_t ws_size,
                              hipStream_t stream) {
  const float* q    = (const float*)d_in[0];
  const float* k    = (const float*)d_in[1];
  const float* v    = (const float*)d_in[2];
  const float* td   = (const float*)d_in[3];
  const int*   mask = (const int*)d_in[4];
  const float* Wq   = (const float*)d_in[5];
  const float* bq   = (const float*)d_in[6];
  const float* Wk   = (const float*)d_in[7];
  const float* bk   = (const float*)d_in[8];
  const float* Wv   = (const float*)d_in[9];
  const float* bv   = (const float*)d_in[10];
  const float* Wo   = (const float*)d_in[11];
  const float* bo   = (const float*)d_in[12];
  const float* gm   = (const float*)d_in[13];

  const size_t MD = (size_t)M_ * D_;      // 8388608
  const size_t WW = (size_t)D_ * D_;      // 1048576
  if (ws_size < (8 * MD + 4 * WW) * sizeof(_Float16)) return;

  _Float16* base = (_Float16*)d_ws;
  _Float16* qh = base;                    // biasN backing (2*MD = B*S*S)
  _Float16* kh = qh + MD;
  _Float16* vh = kh + MD;                 // unused
  _Float16* wq = vh + MD;
  _Float16* wk = wq + WW;
  _Float16* wv = wk + WW;
  _Float16* wo = wv + WW;
  _Float16* Qp = wo + WW;
  _Float16* Kp = Qp + MD;
  _Float16* Vp = Kp + MD;                 // unused
  _Float16* Vt = Vp + MD;
  _Float16* Oa = Vt + MD;
  _Float16* biasN = qh;                   // [B][S][S] f16

  // cast only the 4 weight matrices to f16
  CastArgs ca;
  ca.src[0] = Wq; ca.src[1] = Wk; ca.src[2] = Wv; ca.src[3] = Wo;
  ca.dst[0] = wq; ca.dst[1] = wk; ca.dst[2] = wv; ca.dst[3] = wo;
  int c = 0; ca.cum[0] = 0;
  for (int i = 0; i < 4; ++i) { c += (int)(WW / 8); ca.cum[i + 1] = c; }
  cast_kernel<<<(c + 255) / 256, 256, 0, stream>>>(ca);

  // merged Q/K/V projections + bias precompute (z=3 slice)
  QKVArgs ga;
  ga.A[0] = q;  ga.A[1] = k;  ga.A[2] = v;
  ga.Bt[0] = wq; ga.Bt[1] = wk; ga.Bt[2] = wv;
  ga.bias[0] = bq; ga.bias[1] = bk; ga.bias[2] = bv;
  ga.out[0] = Qp; ga.out[1] = Kp; ga.out[2] = Vt;
  ga.td = td; ga.mask = mask; ga.gptr = gm; ga.biasN = biasN;
  gemm_qkv<<<dim3(64, 8, 4), 256, 0, stream>>>(ga, 0.18033688011112042f);

  attn_kernel<<<1024, 512, 0, stream>>>(Qp, Kp, Vt, biasN, Oa);
  gemm_out<<<dim3(64, 8), 256, 0, stream>>>(Oa, wo, bo, (float*)d_out);
}

// Round 23
// 290.562 us; speedup vs baseline: 1.3187x; 1.0038x over previous
//
#include <hip/hip_runtime.h>
#include <hip/hip_bf16.h>

#define B_ 4
#define S_ 2048
#define D_ 1024
#define H_ 16
#define M_ 8192   // B_*S_

typedef __attribute__((ext_vector_type(8))) _Float16 h8;
typedef __attribute__((ext_vector_type(4))) _Float16 h4;
typedef __attribute__((ext_vector_type(2))) __fp16   fp16x2;
typedef __attribute__((ext_vector_type(8))) short    s8;
typedef __attribute__((ext_vector_type(4))) float    f4;

#define AS1(p) ((const __attribute__((address_space(1))) void*)(p))
#define AS3(p) ((__attribute__((address_space(3))) void*)(p))

__device__ __forceinline__ f4 mfma16(h8 a, h8 b, f4 c) {
  return __builtin_amdgcn_mfma_f32_16x16x32_f16(a, b, c, 0, 0, 0);
}

// ---------------- cast f32 -> f16 (weights only: Wq,Wk,Wv,Wo) ----------------
struct CastArgs {
  const float* src[4];
  _Float16*    dst[4];
  int cum[5];
};

__global__ __launch_bounds__(256) void cast_kernel(CastArgs a) {
  int idx = blockIdx.x * 256 + threadIdx.x;
  if (idx >= a.cum[4]) return;
  int seg = 0;
#pragma unroll
  for (int s = 1; s < 4; ++s) seg += (idx >= a.cum[s]) ? 1 : 0;
  size_t off = (size_t)(idx - a.cum[seg]) * 8;
  const float4* sp = (const float4*)(a.src[seg] + off);
  float4 u = sp[0], v = sp[1];
  union { _Float16 h[8]; h8 v8; } o;
  o.h[0] = (_Float16)u.x; o.h[1] = (_Float16)u.y;
  o.h[2] = (_Float16)u.z; o.h[3] = (_Float16)u.w;
  o.h[4] = (_Float16)v.x; o.h[5] = (_Float16)v.y;
  o.h[6] = (_Float16)v.z; o.h[7] = (_Float16)v.w;
  *(h8*)(a.dst[seg] + off) = o.v8;
}

// ---------------- merged Q/K/V projection GEMM + bias precompute --------------
// z=0..2: pipelined f32->f16 A-path GEMM (round-20 validated).
// z=3:    bias precompute: biasN = mask ? exp(-g*td)/ln2 : -30000 (f16).
struct QKVArgs {
  const float*    A[3];
  const _Float16* Bt[3];
  const float*    bias[3];
  _Float16*       out[3];
  const float*    td;
  const int*      mask;
  const float*    gptr;
  _Float16*       biasN;
};

__global__ __launch_bounds__(256, 3) void gemm_qkv(QKVArgs ga, float scaleQ) {
  __shared__ __align__(16) _Float16 Alds[128 * 64];   // 16 KB f16
  __shared__ __align__(16) _Float16 Blds[128 * 64];   // 16 KB
  const int z = blockIdx.z;
  const int t = threadIdx.x;

  if (z == 3) {
    const float gamma = ga.gptr[0];
    size_t tid = ((size_t)blockIdx.x * 8 + blockIdx.y) * 256 + t;
#pragma unroll
    for (int i = 0; i < 16; ++i) {
      size_t off = (tid + (size_t)i * 131072) * 8;   // 512*256 = 131072 threads
      const float4* tp = (const float4*)(ga.td + off);
      const int4*   mp = (const int4*)(ga.mask + off);
      float4 t0 = tp[0], t1 = tp[1];
      int4   m0 = mp[0], m1 = mp[1];
      union { _Float16 h[8]; h8 v8; } o;
      o.h[0] = m0.x ? (_Float16)(__expf(-gamma * t0.x) * 1.4426950408889634f) : (_Float16)(-30000.0f);
      o.h[1] = m0.y ? (_Float16)(__expf(-gamma * t0.y) * 1.4426950408889634f) : (_Float16)(-30000.0f);
      o.h[2] = m0.z ? (_Float16)(__expf(-gamma * t0.z) * 1.4426950408889634f) : (_Float16)(-30000.0f);
      o.h[3] = m0.w ? (_Float16)(__expf(-gamma * t0.w) * 1.4426950408889634f) : (_Float16)(-30000.0f);
      o.h[4] = m1.x ? (_Float16)(__expf(-gamma * t1.x) * 1.4426950408889634f) : (_Float16)(-30000.0f);
      o.h[5] = m1.y ? (_Float16)(__expf(-gamma * t1.y) * 1.4426950408889634f) : (_Float16)(-30000.0f);
      o.h[6] = m1.z ? (_Float16)(__expf(-gamma * t1.z) * 1.4426950408889634f) : (_Float16)(-30000.0f);
      o.h[7] = m1.w ? (_Float16)(__expf(-gamma * t1.w) * 1.4426950408889634f) : (_Float16)(-30000.0f);
      *(h8*)(ga.biasN + off) = o.v8;
    }
    return;
  }

  const float*    A  = ga.A[z];
  const _Float16* Bt = ga.Bt[z];
  const float*  bias = ga.bias[z];
  _Float16*     Cout = ga.out[z];
  const float scale  = (z == 0) ? scaleQ : 1.0f;
  const int lane = t & 63, w = t >> 6;
  const int wm = w >> 1, wn = w & 1;
  const int m0 = blockIdx.x * 128, n0 = blockIdx.y * 128;
  const int ll = lane & 15, lg = lane >> 4;
  f4 acc[4][4] = {};

  int arow[4], acc_[4];
#pragma unroll
  for (int qq = 0; qq < 4; ++qq) {
    int c2 = qq * 256 + t;
    arow[qq] = c2 >> 3;
    acc_[qq] = c2 & 7;
  }

  float4 a0[4], a1[4];
  auto LOADR = [&](int kt) {
#pragma unroll
    for (int qq = 0; qq < 4; ++qq) {
      const float* src = A + (size_t)(m0 + arow[qq]) * 1024 + kt + acc_[qq] * 8;
      a0[qq] = *(const float4*)src;
      a1[qq] = *(const float4*)(src + 4);
    }
  };
  auto WRITEA = [&]() {
#pragma unroll
    for (int qq = 0; qq < 4; ++qq) {
      union { _Float16 hh[8]; h8 v; } cv;
      cv.hh[0] = (_Float16)a0[qq].x; cv.hh[1] = (_Float16)a0[qq].y;
      cv.hh[2] = (_Float16)a0[qq].z; cv.hh[3] = (_Float16)a0[qq].w;
      cv.hh[4] = (_Float16)a1[qq].x; cv.hh[5] = (_Float16)a1[qq].y;
      cv.hh[6] = (_Float16)a1[qq].z; cv.hh[7] = (_Float16)a1[qq].w;
      *(h8*)((char*)Alds + arow[qq] * 128 + ((acc_[qq] ^ (arow[qq] & 7)) << 4)) = cv.v;
    }
  };
  auto GLOADB = [&](int kt) {
#pragma unroll
    for (int i = 0; i < 4; ++i) {
      int slot = i * 256 + t;
      int r = slot >> 3;
      int gs = ((slot & 7) ^ (r & 7)) * 8;
      __builtin_amdgcn_global_load_lds(AS1(Bt + (size_t)(n0 + r) * 1024 + kt + gs),
                                       AS3((char*)Blds + (i * 256 + w * 64) * 16), 16, 0, 0);
    }
  };

  LOADR(0);
  WRITEA();
  GLOADB(0);
  __syncthreads();

  for (int kt = 0; kt < 1024; kt += 64) {
    if (kt < 960) LOADR(kt + 64);
#pragma unroll
    for (int ks = 0; ks < 2; ++ks) {
      h8 af[4], bf[4];
#pragma unroll
      for (int im = 0; im < 4; ++im) {
        int R = wm * 64 + im * 16 + ll;
        af[im] = *(const h8*)((const char*)Alds + R * 128 + (((ks * 4 + lg) ^ (R & 7)) << 4));
      }
#pragma unroll
      for (int in = 0; in < 4; ++in) {
        int R = wn * 64 + in * 16 + ll;
        bf[in] = *(const h8*)((const char*)Blds + R * 128 + (((ks * 4 + lg) ^ (R & 7)) << 4));
      }
#pragma unroll
      for (int im = 0; im < 4; ++im)
#pragma unroll
        for (int in = 0; in < 4; ++in)
          acc[im][in] = mfma16(af[im], bf[in], acc[im][in]);
    }
    __syncthreads();
    if (kt < 960) {
      WRITEA();
      GLOADB(kt + 64);
    }
    __syncthreads();
  }
#pragma unroll
  for (int im = 0; im < 4; ++im)
#pragma unroll
    for (int in = 0; in < 4; ++in) {
      int col = n0 + wn * 64 + in * 16 + ll;
      float bv = bias[col];
      if (z == 2) {
        int row0 = m0 + wm * 64 + im * 16 + lg * 4;
        int bb = row0 >> 11, s = row0 & 2047;
        union { _Float16 hh[4]; unsigned long long u; } pk;
#pragma unroll
        for (int r = 0; r < 4; ++r)
          pk.hh[r] = (_Float16)(acc[im][in][r] + bv);
        *(unsigned long long*)(Cout + (size_t)((bb * 16 + (col >> 6)) * 64 + (col & 63)) * S_ + s) = pk.u;
      } else {
#pragma unroll
        for (int r = 0; r < 4; ++r) {
          int row = m0 + wm * 64 + im * 16 + lg * 4 + r;
          Cout[(size_t)row * 1024 + col] = (_Float16)((acc[im][in][r] + bv) * scale);
        }
      }
    }
}

// ---------------- output projection GEMM (f16 A, f32 out) — unchanged --------
__global__ __launch_bounds__(256, 3) void gemm_out(
    const _Float16* __restrict__ A,
    const _Float16* __restrict__ Bt,
    const float*    __restrict__ bias,
    float*          __restrict__ Cout)
{
  __shared__ __align__(16) _Float16 Alds[128 * 64];
  __shared__ __align__(16) _Float16 Blds[128 * 64];
  const int t = threadIdx.x;
  const int lane = t & 63, w = t >> 6;
  const int wm = w >> 1, wn = w & 1;
  const int m0 = blockIdx.x * 128, n0 = blockIdx.y * 128;
  const int ll = lane & 15, lg = lane >> 4;
  f4 acc[4][4] = {};

  for (int kt = 0; kt < 1024; kt += 64) {
    __syncthreads();
#pragma unroll
    for (int i = 0; i < 4; ++i) {
      int slot = i * 256 + t;
      int r = slot >> 3;
      int gs = ((slot & 7) ^ (r & 7)) * 8;
      __builtin_amdgcn_global_load_lds(AS1(A  + (size_t)(m0 + r) * 1024 + kt + gs),
                                       AS3((char*)Alds + (i * 256 + w * 64) * 16), 16, 0, 0);
      __builtin_amdgcn_global_load_lds(AS1(Bt + (size_t)(n0 + r) * 1024 + kt + gs),
                                       AS3((char*)Blds + (i * 256 + w * 64) * 16), 16, 0, 0);
    }
    __syncthreads();
#pragma unroll
    for (int ks = 0; ks < 2; ++ks) {
      h8 af[4], bf[4];
#pragma unroll
      for (int im = 0; im < 4; ++im) {
        int R = wm * 64 + im * 16 + ll;
        af[im] = *(const h8*)((const char*)Alds + R * 128 + (((ks * 4 + lg) ^ (R & 7)) << 4));
      }
#pragma unroll
      for (int in = 0; in < 4; ++in) {
        int R = wn * 64 + in * 16 + ll;
        bf[in] = *(const h8*)((const char*)Blds + R * 128 + (((ks * 4 + lg) ^ (R & 7)) << 4));
      }
#pragma unroll
      for (int im = 0; im < 4; ++im)
#pragma unroll
        for (int in = 0; in < 4; ++in)
          acc[im][in] = mfma16(af[im], bf[in], acc[im][in]);
    }
  }
#pragma unroll
  for (int im = 0; im < 4; ++im)
#pragma unroll
    for (int in = 0; in < 4; ++in) {
      int col = n0 + wn * 64 + in * 16 + ll;
      float bv = bias[col];
#pragma unroll
      for (int r = 0; r < 4; ++r) {
        int row = m0 + wm * 64 + im * 16 + lg * 4 + r;
        Cout[(size_t)row * 1024 + col] = acc[im][in][r] + bv;
      }
    }
}

// ---------------- fused flash attention (round-22 validated + half-P) ---------
// Identical sync structure (one __syncthreads per body). Wave-LOCAL change:
// P buffer halved to 1KB/wave (rows 64B, swizzle byte ^= (ll&3)<<4); body
// softmax/PV split into two k-halves (write jf{0,1} -> PV ks0 -> write jf{2,3}
// -> PV ks1); same-wave write->read ordering is compiler-managed (same
// mechanism as all passing rounds). LDS = 16K K + 16K V + 8K P = 40960
// -> 4 blocks/CU = 32 waves/CU (was 3 / 24).
#define KL_OFF   0
#define VL_OFF   16384
#define PL_OFF   32768

__global__ __launch_bounds__(512, 2) void attn_kernel(
    const _Float16* __restrict__ Qp,    // [8192][1024], pre-scaled by 1/(8 ln2)
    const _Float16* __restrict__ Kp,    // [8192][1024]
    const _Float16* __restrict__ Vt,    // [(b*16+h)*64+hd][2048]
    const _Float16* __restrict__ biasN, // [4][2048(q)][2048(k)], pre-scaled 1/ln2
    _Float16*       __restrict__ Oa)    // [8192][1024]
{
  __shared__ __align__(16) char lds[40960];
  const int t = threadIdx.x;
  const int lane = t & 63, w = t >> 6;          // w = 0..7
  const int ll = lane & 15, lg = lane >> 4;
  // XCD-chunked swizzle (grid 1024 = 8 XCD x 128)
  const int vbid = ((int)blockIdx.x & 7) * 128 + ((int)blockIdx.x >> 3);
  const int b  = vbid >> 8;
  const int h  = (vbid >> 4) & 15;
  const int qg = vbid & 15;
  const int q0 = qg * 128 + w * 16;     // wave q base

  const int lrow = lane >> 3;           // staging row-in-group
  const int lcs  = (lane & 7) ^ lrow;   // pre-swizzled chunk

  const _Float16* Kg = Kp + (size_t)b * S_ * D_ + h * 64;
  const _Float16* Vg = Vt + (size_t)(b * 16 + h) * 64 * S_;
  const _Float16* Bg = biasN + ((size_t)b * S_ + q0 + ll) * S_;  // per-lane row q

  char* pbase = lds + PL_OFF + w * 1024;        // 1KB per wave
  const int xsw = (ll & 3) << 4;                // 16B-granular row swizzle

  // Q fragments (B-operand of swapped QK)
  const size_t qrow = (size_t)(b * S_ + q0 + ll) * D_ + h * 64;
  h8 qf0 = *(const h8*)(Qp + qrow + lg * 8);
  h8 qf1 = *(const h8*)(Qp + qrow + 32 + lg * 8);

  float lsum = 0.f;                     // all elements of this lane are q = ll
  f4 accO[4] = {};                      // O^T[d = df*16+lg*4+r][q = ll]

  // stage one 64-k K/V tile: 16 gloads distributed 2-per-wave over 8 waves
  auto STAGE = [&](int kt, int bufb) {
#pragma unroll
    for (int j = 0; j < 2; ++j) {
      int i = w * 2 + j;                // 0..15
      int g = i & 7;
      int row8 = g * 8 + lrow;
      const _Float16* src;
      char* dst;
      if (i < 8) {
        src = Kg + (size_t)(kt + row8) * D_ + lcs * 8;
        dst = lds + KL_OFF + bufb * 8192 + g * 1024;
      } else {
        src = Vg + (size_t)row8 * S_ + kt + lcs * 8;
        dst = lds + VL_OFF + bufb * 8192 + g * 1024;
      }
      __builtin_amdgcn_global_load_lds(AS1(src), AS3(dst), 16, 0, 0);
    }
  };
  auto BLOAD = [&](int kt, h4 (&dst)[4]) {
#pragma unroll
    for (int jf = 0; jf < 4; ++jf)
      dst[jf] = *(const h4*)(Bg + kt + 16 * jf + lg * 4);
  };

  auto BODY = [&](int tt, h4 (&bc)[4], h4 (&bn)[4]) {
    const int bufb = tt & 1;
    const char* Kb = lds + KL_OFF + bufb * 8192;
    const char* Vb = lds + VL_OFF + bufb * 8192;

    // S^T = K . Q^T, bias as MFMA C-init.
    f4 accS[4];
#pragma unroll
    for (int jf = 0; jf < 4; ++jf) {
      accS[jf][0] = (float)bc[jf][0];
      accS[jf][1] = (float)bc[jf][1];
      accS[jf][2] = (float)bc[jf][2];
      accS[jf][3] = (float)bc[jf][3];
    }
    __builtin_amdgcn_s_setprio(1);
#pragma unroll
    for (int jf = 0; jf < 4; ++jf) {
      int row = jf * 16 + ll;
      h8 k0 = *(const h8*)(Kb + row * 128 + (((lg)     ^ (row & 7)) << 4));
      h8 k1 = *(const h8*)(Kb + row * 128 + (((4 + lg) ^ (row & 7)) << 4));
      accS[jf] = mfma16(k0, qf0, accS[jf]);
      accS[jf] = mfma16(k1, qf1, accS[jf]);
    }
    __builtin_amdgcn_s_setprio(0);

    // issue next tile mid-body: drained by the end-of-body __syncthreads
    if (tt < 31) {
      STAGE((tt + 1) * 64, bufb ^ 1);
      BLOAD((tt + 1) * 64, bn);
    }

    // two k-halves: write P half -> PV half (P buffer is 1KB/wave, reused)
#pragma unroll
    for (int half = 0; half < 2; ++half) {
      // P^T = 2^(S^T) for jf = 2*half, 2*half+1 -> slots (jf&1)
#pragma unroll
      for (int j2 = 0; j2 < 2; ++j2) {
        int jf = half * 2 + j2;
        float p0, p1, p2, p3;
        asm("v_exp_f32 %0, %1" : "=v"(p0) : "v"(accS[jf][0]));
        asm("v_exp_f32 %0, %1" : "=v"(p1) : "v"(accS[jf][1]));
        asm("v_exp_f32 %0, %1" : "=v"(p2) : "v"(accS[jf][2]));
        asm("v_exp_f32 %0, %1" : "=v"(p3) : "v"(accS[jf][3]));
        lsum += (p0 + p1) + (p2 + p3);
        union { fp16x2 hh[2]; unsigned long long u; } wv;
        wv.hh[0] = __builtin_amdgcn_cvt_pkrtz(p0, p1);
        wv.hh[1] = __builtin_amdgcn_cvt_pkrtz(p2, p3);
        // byte = 2k' = 32*(jf&1) + 8*lg (+2r), row ll, swizzle ^xsw
        *(unsigned long long*)(pbase + ll * 64 + ((32 * j2 + 8 * lg) ^ xsw)) = wv.u;
      }
      // O^T += V^T . P^T for this half (pf: k' = lg*8..+7 -> byte 16*lg)
      h8 pf = *(const h8*)(pbase + ll * 64 + ((16 * lg) ^ xsw));
      __builtin_amdgcn_s_setprio(1);
#pragma unroll
      for (int df = 0; df < 4; ++df) {
        int vrow = df * 16 + ll;
        h8 vfr = *(const h8*)(Vb + vrow * 128 + (((half * 4 + lg) ^ (vrow & 7)) << 4));
        accO[df] = mfma16(vfr, pf, accO[df]);
      }
      __builtin_amdgcn_s_setprio(0);
    }

    __syncthreads();   // drains stage(tt+1) + WAR for buf[bufb]
  };

  h4 bA[4], bB[4];

  // prologue
  STAGE(0, 0);
  BLOAD(0, bA);
  __syncthreads();     // tile 0 resident for all waves

  for (int tt = 0; tt < 32; tt += 2) {  // 2x unroll: bias regs ping-pong
    BODY(tt,     bA, bB);
    BODY(tt + 1, bB, bA);
  }

  // final: sum partials across the 4 lg-groups holding the same q = ll
  lsum += __shfl_xor(lsum, 16);
  lsum += __shfl_xor(lsum, 32);
  float linv = 1.0f / lsum;
#pragma unroll
  for (int df = 0; df < 4; ++df)
#pragma unroll
    for (int r = 0; r < 4; ++r) {
      size_t orow = (size_t)(b * S_ + q0 + ll) * D_ + h * 64 + df * 16 + lg * 4 + r;
      Oa[orow] = (_Float16)(accO[df][r] * linv);
    }
}

// ---------------- launcher ----------------
extern "C" void kernel_launch(void* const* d_in, const int* in_sizes, int n_in,
                              void* d_out, int out_size, void* d_ws, size_t ws_size,
                              hipStream_t stream) {
  const float* q    = (const float*)d_in[0];
  const float* k    = (const float*)d_in[1];
  const float* v    = (const float*)d_in[2];
  const float* td   = (const float*)d_in[3];
  const int*   mask = (const int*)d_in[4];
  const float* Wq   = (const float*)d_in[5];
  const float* bq   = (const float*)d_in[6];
  const float* Wk   = (const float*)d_in[7];
  const float* bk   = (const float*)d_in[8];
  const float* Wv   = (const float*)d_in[9];
  const float* bv   = (const float*)d_in[10];
  const float* Wo   = (const float*)d_in[11];
  const float* bo   = (const float*)d_in[12];
  const float* gm   = (const float*)d_in[13];

  const size_t MD = (size_t)M_ * D_;      // 8388608
  const size_t WW = (size_t)D_ * D_;      // 1048576
  if (ws_size < (8 * MD + 4 * WW) * sizeof(_Float16)) return;

  _Float16* base = (_Float16*)d_ws;
  _Float16* qh = base;                    // biasN backing (2*MD = B*S*S)
  _Float16* kh = qh + MD;
  _Float16* vh = kh + MD;                 // unused
  _Float16* wq = vh + MD;
  _Float16* wk = wq + WW;
  _Float16* wv = wk + WW;
  _Float16* wo = wv + WW;
  _Float16* Qp = wo + WW;
  _Float16* Kp = Qp + MD;
  _Float16* Vp = Kp + MD;                 // unused
  _Float16* Vt = Vp + MD;
  _Float16* Oa = Vt + MD;
  _Float16* biasN = qh;                   // [B][S][S] f16

  // cast only the 4 weight matrices to f16
  CastArgs ca;
  ca.src[0] = Wq; ca.src[1] = Wk; ca.src[2] = Wv; ca.src[3] = Wo;
  ca.dst[0] = wq; ca.dst[1] = wk; ca.dst[2] = wv; ca.dst[3] = wo;
  int c = 0; ca.cum[0] = 0;
  for (int i = 0; i < 4; ++i) { c += (int)(WW / 8); ca.cum[i + 1] = c; }
  cast_kernel<<<(c + 255) / 256, 256, 0, stream>>>(ca);

  // merged Q/K/V projections + bias precompute (z=3 slice)
  QKVArgs ga;
  ga.A[0] = q;  ga.A[1] = k;  ga.A[2] = v;
  ga.Bt[0] = wq; ga.Bt[1] = wk; ga.Bt[2] = wv;
  ga.bias[0] = bq; ga.bias[1] = bk; ga.bias[2] = bv;
  ga.out[0] = Qp; ga.out[1] = Kp; ga.out[2] = Vt;
  ga.td = td; ga.mask = mask; ga.gptr = gm; ga.biasN = biasN;
  gemm_qkv<<<dim3(64, 8, 4), 256, 0, stream>>>(ga, 0.18033688011112042f);

  attn_kernel<<<1024, 512, 0, stream>>>(Qp, Kp, Vt, biasN, Oa);
  gemm_out<<<dim3(64, 8), 256, 0, stream>>>(Oa, wo, bo, (float*)d_out);
}